// Round 4
// baseline (767.503 us; speedup 1.0000x reference)
//
#include <hip/hip_runtime.h>

#define B_ 4
#define C_ 512
#define CI_ 256
#define N_ 4096
#define SCALE_PAM 0.04419417382415922f  // 1/sqrt(512)
#define SCALE_CAM (1.0f/64.0f)          // 1/sqrt(4096)
#define SHIFT_PAM 8.0f                  // fixed softmax shift (logits bounded ~|8|)

typedef float v4f __attribute__((ext_vector_type(4)));
typedef short v8s __attribute__((ext_vector_type(8)));

__device__ __forceinline__ unsigned short f2bf(float f) {
  unsigned int u = __float_as_uint(f);
  u = (u + 0x7FFFu + ((u >> 16) & 1u)) >> 16;
  return (unsigned short)u;
}
__device__ __forceinline__ float bf2f(unsigned short s) {
  return __uint_as_float(((unsigned int)s) << 16);
}
__device__ __forceinline__ v8s ld8(const unsigned short* p) {
  v8s r; *(int4*)&r = *(const int4*)p; return r;
}
__device__ __forceinline__ v4f mfma16(v8s a, v8s b, v4f c) {
  return __builtin_amdgcn_mfma_f32_16x16x32_bf16(a, b, c, 0, 0, 0);
}

// ---------------------------------------------------------------------------
// K0a: transpose+convert x fp32 [b][c][n] -> xT bf16 [b][n][c]. 64x64 tiles.
// ---------------------------------------------------------------------------
__global__ __launch_bounds__(256) void k_xT(const float* __restrict__ x,
                                            unsigned short* __restrict__ xT) {
  const int b = blockIdx.z, c0 = blockIdx.y * 64, n0 = blockIdx.x * 64;
  const int t = threadIdx.x;
  __shared__ unsigned short ts[64 * 72];  // [n][c]
  const int cl = t >> 2, nseg = (t & 3) * 16;
  const float* xr = x + ((size_t)b * C_ + c0 + cl) * N_ + n0 + nseg;
#pragma unroll
  for (int k = 0; k < 4; ++k) {
    float4 f = *(const float4*)(xr + k * 4);
    ts[(nseg + k * 4 + 0) * 72 + cl] = f2bf(f.x);
    ts[(nseg + k * 4 + 1) * 72 + cl] = f2bf(f.y);
    ts[(nseg + k * 4 + 2) * 72 + cl] = f2bf(f.z);
    ts[(nseg + k * 4 + 3) * 72 + cl] = f2bf(f.w);
  }
  __syncthreads();
  const int nl = t >> 2, cseg = (t & 3) * 16;
  int4 a0 = *(int4*)&ts[nl * 72 + cseg];
  int4 a1 = *(int4*)&ts[nl * 72 + cseg + 8];
  unsigned short* dst = xT + ((size_t)b * N_ + n0 + nl) * C_ + c0 + cseg;
  *(int4*)dst = a0; *(int4*)(dst + 8) = a1;
}

// ---------------------------------------------------------------------------
// K0b: convert wq/wk/wv fp32 -> wb bf16 [1024][512]
// ---------------------------------------------------------------------------
__global__ __launch_bounds__(256) void k_wb(const float* __restrict__ wq,
                                            const float* __restrict__ wk,
                                            const float* __restrict__ wv,
                                            unsigned short* __restrict__ wb) {
  int e = (blockIdx.x * 256 + threadIdx.x) * 4;
  int row = e >> 9, col = e & 511;
  const float* src = (row < 256) ? &wq[row * 512 + col]
                   : (row < 512) ? &wk[(row - 256) * 512 + col]
                                 : &wv[(row - 512) * 512 + col];
  float4 f = *(const float4*)src;
  ushort4 o = { f2bf(f.x), f2bf(f.y), f2bf(f.z), f2bf(f.w) };
  *(ushort4*)&wb[e] = o;
}

// ---------------------------------------------------------------------------
// K1: QKV conv via MFMA, 128o x 128n tile, 512 thr (8 waves, 2x4).
// A = wb [o][c] frags, B = xT [n][c] frags.
// q/k written transposed (qT/kT [n][o]) via LDS; v natural [c][n] bf16.
// ---------------------------------------------------------------------------
__global__ __launch_bounds__(512, 4) void k_qkv(
    const unsigned short* __restrict__ wb, const unsigned short* __restrict__ xT,
    const float* __restrict__ bq, const float* __restrict__ bk, const float* __restrict__ bv,
    unsigned short* __restrict__ qT, unsigned short* __restrict__ kT,
    unsigned short* __restrict__ vbf) {
  const int b = blockIdx.z, o0 = blockIdx.y * 128, n0 = blockIdx.x * 128;
  const int t = threadIdx.x, wave = t >> 6, lane = t & 63;
  const int la = lane & 15, quad = lane >> 4;
  const int ow = wave & 1, nw = wave >> 1;
  const unsigned short* xTb = xT + (size_t)b * N_ * C_;
  __shared__ unsigned short tp[128 * 136];

  v4f acc[4][2];
#pragma unroll
  for (int i = 0; i < 4; ++i)
#pragma unroll
    for (int j = 0; j < 2; ++j) acc[i][j] = (v4f){0.f, 0.f, 0.f, 0.f};

  unsigned ar[4], br[2];
#pragma unroll
  for (int oi = 0; oi < 4; ++oi) ar[oi] = (unsigned)(o0 + ow * 64 + oi * 16 + la) * 512u;
#pragma unroll
  for (int nj = 0; nj < 2; ++nj) br[nj] = (unsigned)(n0 + nw * 32 + nj * 16 + la) * 512u;

#pragma unroll 4
  for (int s = 0; s < 16; ++s) {
    const int kof = s * 32 + quad * 8;
    v8s b0 = ld8(&xTb[br[0] + kof]);
    v8s b1 = ld8(&xTb[br[1] + kof]);
#pragma unroll
    for (int oi = 0; oi < 4; ++oi) {
      v8s a = ld8(&wb[ar[oi] + kof]);
      acc[oi][0] = mfma16(a, b0, acc[oi][0]);
      acc[oi][1] = mfma16(a, b1, acc[oi][1]);
    }
  }

  if (o0 >= 512) {
#pragma unroll
    for (int oi = 0; oi < 4; ++oi)
#pragma unroll
      for (int nj = 0; nj < 2; ++nj)
#pragma unroll
        for (int r = 0; r < 4; ++r) {
          int og = o0 - 512 + ow * 64 + oi * 16 + quad * 4 + r;
          int ng = n0 + nw * 32 + nj * 16 + la;
          vbf[((size_t)b * C_ + og) * N_ + ng] = f2bf(acc[oi][nj][r] + bv[og]);
        }
  } else {
    const float* bias = (o0 < 256) ? bq : bk;
#pragma unroll
    for (int oi = 0; oi < 4; ++oi)
#pragma unroll
      for (int nj = 0; nj < 2; ++nj)
#pragma unroll
        for (int r = 0; r < 4; ++r) {
          int ol = ow * 64 + oi * 16 + quad * 4 + r;
          int nl = nw * 32 + nj * 16 + la;
          tp[nl * 136 + ol] = f2bf(acc[oi][nj][r] + bias[(o0 & 255) + ol]);
        }
    __syncthreads();
    const int nl = t >> 2;
    unsigned short* dstb = ((o0 < 256) ? qT : kT)
        + ((size_t)b * N_ + n0 + nl) * CI_ + (o0 & 255);
#pragma unroll
    for (int chunk = 0; chunk < 4; ++chunk) {
      int oseg = chunk * 32 + (t & 3) * 8;
      *(int4*)&dstb[oseg] = *(int4*)&tp[nl * 136 + oseg];
    }
  }
}

// ---------------------------------------------------------------------------
// K2: fused PAM, fixed-shift flash. 512 thr (8 waves), i-tile 32, j-tile 64.
// grid (128 i-tiles, B) = 512 blocks -> 2 blocks/CU.
// S-phase: wave w -> subtile (iw=w&1, jw=w>>1), split-K for 2 indep chains.
// PV-phase: wave w -> 64 channels [w*64, w*64+64).
// One barrier per j-iter (double-buffered P).
// Epilogue: sa=tanh(gp*pam+x) -> sabf [c][n] + saT [n][c] (swizzled staging).
// ---------------------------------------------------------------------------
__global__ __launch_bounds__(512, 4) void k_pam(
    const unsigned short* __restrict__ qT, const unsigned short* __restrict__ kT,
    const unsigned short* __restrict__ vbf, const float* __restrict__ x,
    const float* __restrict__ gamma_pam,
    unsigned short* __restrict__ sabf, unsigned short* __restrict__ saT) {
  const int b = blockIdx.y, i0 = blockIdx.x * 32;
  const int t = threadIdx.x, wave = t >> 6, lane = t & 63;
  const int la = lane & 15, quad = lane >> 4;
  const int iw = wave & 1, jw = wave >> 1;
  const int cb = wave * 64;

  __shared__ unsigned short pa[2][32 * 72];   // P bf16 [i][j], dbuf
  __shared__ unsigned short st[16 * 520];     // saT staging (16 rows)
  __shared__ float l_lds[32];
  if (t < 32) l_lds[t] = 0.f;

  const unsigned short* qTb = qT + (size_t)b * N_ * CI_;
  const unsigned short* kTb = kT + (size_t)b * N_ * CI_;
  const unsigned short* vb  = vbf + (size_t)b * C_ * N_;

  // Q A-frags, register-resident (one 16-row i-subtile per wave)
  v8s qf[8];
  {
    const unsigned short* qrow = qTb + (size_t)(i0 + iw * 16 + la) * CI_ + quad * 8;
#pragma unroll
    for (int s = 0; s < 8; ++s) qf[s] = ld8(qrow + s * 32);
  }

  v4f acc[4][2];
#pragma unroll
  for (int ct = 0; ct < 4; ++ct)
#pragma unroll
    for (int it = 0; it < 2; ++it) acc[ct][it] = (v4f){0.f, 0.f, 0.f, 0.f};
  float lsum[4] = {0.f, 0.f, 0.f, 0.f};

  unsigned voff[4];
#pragma unroll
  for (int ct = 0; ct < 4; ++ct) voff[ct] = (unsigned)(cb + ct * 16 + la) * N_;

  int buf = 0;
  for (int j0 = 0; j0 < N_; j0 += 64) {
    // ---- S = Q K^T, split-K into two independent chains for MFMA ILP ----
    const unsigned short* krow = kTb + (size_t)(j0 + jw * 16 + la) * CI_ + quad * 8;
    v4f sA = (v4f){0.f, 0.f, 0.f, 0.f}, sB = sA;
#pragma unroll
    for (int sh = 0; sh < 4; ++sh) {
      sA = mfma16(qf[sh], ld8(krow + sh * 32), sA);
      sB = mfma16(qf[sh + 4], ld8(krow + (sh + 4) * 32), sB);
    }
    // ---- prefetch V frags for this j-tile (independent of barrier) ----
    v8s vf[4][2];
#pragma unroll
    for (int ct = 0; ct < 4; ++ct)
#pragma unroll
      for (int ks = 0; ks < 2; ++ks)
        vf[ct][ks] = ld8(&vb[voff[ct] + j0 + ks * 32 + quad * 8]);
    // ---- P = exp(S*scale - shift) ----
#pragma unroll
    for (int r = 0; r < 4; ++r) {
      float p = __expf((sA[r] + sB[r]) * SCALE_PAM - SHIFT_PAM);
      lsum[r] += p;
      pa[buf][(iw * 16 + quad * 4 + r) * 72 + jw * 16 + la] = f2bf(p);
    }
    __syncthreads();
    // ---- PV: acc[c][i] += V[c][j] P^T[j][i] ----
#pragma unroll
    for (int it = 0; it < 2; ++it)
#pragma unroll
      for (int ks = 0; ks < 2; ++ks) {
        v8s pf; *(int4*)&pf = *(const int4*)&pa[buf][(it * 16 + la) * 72 + ks * 32 + quad * 8];
#pragma unroll
        for (int ct = 0; ct < 4; ++ct)
          acc[ct][it] = mfma16(vf[ct][ks], pf, acc[ct][it]);
      }
    buf ^= 1;
  }

  // ---- reduce l per i-row ----
#pragma unroll
  for (int r = 0; r < 4; ++r) {
    float v = lsum[r];
    v += __shfl_xor(v, 1); v += __shfl_xor(v, 2);
    v += __shfl_xor(v, 4); v += __shfl_xor(v, 8);
    if (la == 0) atomicAdd(&l_lds[iw * 16 + quad * 4 + r], v);
  }
  __syncthreads();

  const float gpv = gamma_pam[0];
  float linv[2];
#pragma unroll
  for (int it = 0; it < 2; ++it)
    linv[it] = 1.0f / (l_lds[it * 16 + la] * (float)N_);

  // ---- epilogue: 2 halves of 16 i-rows each ----
#pragma unroll
  for (int half = 0; half < 2; ++half) {
    const int it = half;
#pragma unroll
    for (int ct = 0; ct < 4; ++ct)
#pragma unroll
      for (int r = 0; r < 4; ++r) {
        int c = cb + ct * 16 + quad * 4 + r;
        size_t gi = ((size_t)b * C_ + c) * N_ + i0 + it * 16 + la;
        float sv = tanhf(fmaf(gpv, acc[ct][it][r] * linv[it], x[gi]));
        unsigned short us = f2bf(sv);
        sabf[gi] = us;
        st[la * 520 + ((c + la * 32) & 511)] = us;
      }
    __syncthreads();
    {
      const int row = t >> 5, l5 = t & 31;  // 16 rows x 512 cols
      unsigned short* dst = saT + ((size_t)b * N_ + i0 + half * 16 + row) * C_;
#pragma unroll
      for (int chunk = 0; chunk < 2; ++chunk) {
        int c0s = chunk * 256 + l5 * 8;
        int csw = (c0s + row * 32) & 511;
        *(int4*)&dst[c0s] = *(int4*)&st[row * 520 + csw];
      }
    }
    __syncthreads();
  }
}

// ---------------------------------------------------------------------------
// K3: CAM gram via MFMA, K-split 4. e_part[ks][b][c][d] = scale * sum sa_c sa_d
// ---------------------------------------------------------------------------
__global__ __launch_bounds__(256) void k_cam_e(const unsigned short* __restrict__ sabf,
                                               float* __restrict__ e_part) {
  const int b = blockIdx.z, ks = blockIdx.y;
  const int c0 = (blockIdx.x & 7) * 64, d0 = (blockIdx.x >> 3) * 64;
  const int t = threadIdx.x, wave = t >> 6, lane = t & 63;
  const int la = lane & 15, quad = lane >> 4;
  const int cw = wave & 1, dw = wave >> 1;
  const unsigned short* sb = sabf + (size_t)b * C_ * N_;

  v4f acc[2][2];
#pragma unroll
  for (int i = 0; i < 2; ++i)
#pragma unroll
    for (int j = 0; j < 2; ++j) acc[i][j] = (v4f){0.f, 0.f, 0.f, 0.f};

  const size_t ar0 = (size_t)(c0 + cw * 32 + la) * N_;
  const size_t br0 = (size_t)(d0 + dw * 32 + la) * N_;
#pragma unroll 4
  for (int s = 0; s < 32; ++s) {
    const int kof = ks * 1024 + s * 32 + quad * 8;
    v8s a0 = ld8(&sb[ar0 + kof]);
    v8s a1 = ld8(&sb[ar0 + (size_t)16 * N_ + kof]);
    v8s b0 = ld8(&sb[br0 + kof]);
    v8s b1 = ld8(&sb[br0 + (size_t)16 * N_ + kof]);
    acc[0][0] = mfma16(a0, b0, acc[0][0]);
    acc[0][1] = mfma16(a0, b1, acc[0][1]);
    acc[1][0] = mfma16(a1, b0, acc[1][0]);
    acc[1][1] = mfma16(a1, b1, acc[1][1]);
  }
  float* ep = e_part + ((size_t)(ks * B_ + b)) * C_ * C_;
#pragma unroll
  for (int i = 0; i < 2; ++i)
#pragma unroll
    for (int j = 0; j < 2; ++j)
#pragma unroll
      for (int r = 0; r < 4; ++r) {
        int c = c0 + cw * 32 + i * 16 + quad * 4 + r;
        int d = d0 + dw * 32 + j * 16 + la;
        ep[(size_t)c * C_ + d] = acc[i][j][r] * SCALE_CAM;
      }
}

// ---------------------------------------------------------------------------
// K4: CAM softmax (min-trick), sums 4 K-split parts, writes attn bf16 (/C folded).
// ---------------------------------------------------------------------------
__global__ __launch_bounds__(64) void k_cam_softmax(const float* __restrict__ e_part,
                                                    unsigned short* __restrict__ attnb) {
  const int c = blockIdx.x, b = blockIdx.y, lane = threadIdx.x;
  size_t roff = ((size_t)b * C_ + c) * C_;
  float vals[8];
#pragma unroll
  for (int r = 0; r < 8; ++r) {
    int d = lane + r * 64;
    float s = 0.f;
#pragma unroll
    for (int p = 0; p < 4; ++p) s += e_part[(size_t)(p * B_) * C_ * C_ + roff + d];
    vals[r] = s;
  }
  float mn = vals[0];
#pragma unroll
  for (int r = 1; r < 8; ++r) mn = fminf(mn, vals[r]);
#pragma unroll
  for (int m = 32; m >= 1; m >>= 1) mn = fminf(mn, __shfl_xor(mn, m));
  float sum = 0.f;
#pragma unroll
  for (int r = 0; r < 8; ++r) { vals[r] = __expf(mn - vals[r]); sum += vals[r]; }
#pragma unroll
  for (int m = 32; m >= 1; m >>= 1) sum += __shfl_xor(sum, m);
  float sc = (1.0f / (float)C_) / sum;
#pragma unroll
  for (int r = 0; r < 8; ++r) attnb[roff + lane + r * 64] = f2bf(vals[r] * sc);
}

// ---------------------------------------------------------------------------
// K5: out = gamma_cam * (attn @ sa) + sa.  128c x 128n tile, 512 thr.
// A = attn bf16 [c][d], B = saT [n][d]; residual from sabf (bf16).
// ---------------------------------------------------------------------------
__global__ __launch_bounds__(512, 4) void k_cam_out(
    const unsigned short* __restrict__ attnb, const unsigned short* __restrict__ saT,
    const unsigned short* __restrict__ sabf, const float* __restrict__ gamma_cam,
    float* __restrict__ out) {
  const int b = blockIdx.z, c0 = blockIdx.y * 128, n0 = blockIdx.x * 128;
  const int t = threadIdx.x, wave = t >> 6, lane = t & 63;
  const int la = lane & 15, quad = lane >> 4;
  const int cw = wave & 1, nw = wave >> 1;
  const unsigned short* ab = attnb + (size_t)b * C_ * C_;
  const unsigned short* sTb = saT + (size_t)b * N_ * C_;

  v4f acc[4][2];
#pragma unroll
  for (int i = 0; i < 4; ++i)
#pragma unroll
    for (int j = 0; j < 2; ++j) acc[i][j] = (v4f){0.f, 0.f, 0.f, 0.f};

  unsigned ar[4], br[2];
#pragma unroll
  for (int ci = 0; ci < 4; ++ci) ar[ci] = (unsigned)(c0 + cw * 64 + ci * 16 + la) * 512u;
#pragma unroll
  for (int nj = 0; nj < 2; ++nj) br[nj] = (unsigned)(n0 + nw * 32 + nj * 16 + la) * 512u;

#pragma unroll 4
  for (int s = 0; s < 16; ++s) {
    const int kof = s * 32 + quad * 8;
    v8s b0 = ld8(&sTb[br[0] + kof]);
    v8s b1 = ld8(&sTb[br[1] + kof]);
#pragma unroll
    for (int ci = 0; ci < 4; ++ci) {
      v8s a = ld8(&ab[ar[ci] + kof]);
      acc[ci][0] = mfma16(a, b0, acc[ci][0]);
      acc[ci][1] = mfma16(a, b1, acc[ci][1]);
    }
  }
  const float gc = gamma_cam[0];
#pragma unroll
  for (int ci = 0; ci < 4; ++ci)
#pragma unroll
    for (int nj = 0; nj < 2; ++nj)
#pragma unroll
      for (int r = 0; r < 4; ++r) {
        int c = c0 + cw * 64 + ci * 16 + quad * 4 + r;
        int n = n0 + nw * 32 + nj * 16 + la;
        size_t gi = ((size_t)b * C_ + c) * N_ + n;
        out[gi] = fmaf(gc, acc[ci][nj][r], bf2f(sabf[gi]));
      }
}

// ---------------------------------------------------------------------------
extern "C" void kernel_launch(void* const* d_in, const int* in_sizes, int n_in,
                              void* d_out, int out_size, void* d_ws, size_t ws_size,
                              hipStream_t stream) {
  const float* x  = (const float*)d_in[0];
  const float* wq = (const float*)d_in[1];
  const float* bq = (const float*)d_in[2];
  const float* wk = (const float*)d_in[3];
  const float* bk = (const float*)d_in[4];
  const float* wv = (const float*)d_in[5];
  const float* bv = (const float*)d_in[6];
  const float* gp = (const float*)d_in[7];
  const float* gc = (const float*)d_in[8];
  float* out = (float*)d_out;

  char* ws = (char*)d_ws;
  unsigned short* qT   = (unsigned short*)(ws);               // 8.39 MB
  unsigned short* kT   = (unsigned short*)(ws + 8388608);     // 8.39 MB
  unsigned short* vbf  = (unsigned short*)(ws + 16777216);    // 16.78 MB
  unsigned short* xT   = (unsigned short*)(ws + 33554432);    // 16.78 MB
  unsigned short* wb   = (unsigned short*)(ws + 50331648);    // 1.05 MB
  unsigned short* sabf = (unsigned short*)(ws + 51380224);    // 16.78 MB
  unsigned short* saT  = (unsigned short*)(ws + 68157440);    // 16.78 MB
  float*          ep   = (float*)(ws + 84934656);             // 16.78 MB
  unsigned short* atb  = (unsigned short*)(ws + 101711872);   // 2.10 MB
  // total ~104 MB

  k_xT<<<dim3(64, 8, B_), 256, 0, stream>>>(x, xT);
  k_wb<<<dim3(512), 256, 0, stream>>>(wq, wk, wv, wb);
  k_qkv<<<dim3(32, 8, B_), 512, 0, stream>>>(wb, xT, bq, bk, bv, qT, kT, vbf);
  k_pam<<<dim3(128, B_), 512, 0, stream>>>(qT, kT, vbf, x, gp, sabf, saT);
  k_cam_e<<<dim3(64, 4, B_), 256, 0, stream>>>(sabf, ep);
  k_cam_softmax<<<dim3(C_, B_), 64, 0, stream>>>(ep, atb);
  k_cam_out<<<dim3(32, 4, B_), 512, 0, stream>>>(atb, saT, sabf, gc, out);
}

// Round 5
// 484.647 us; speedup vs baseline: 1.5836x; 1.5836x over previous
//
#include <hip/hip_runtime.h>

#define B_ 4
#define C_ 512
#define CI_ 256
#define N_ 4096
#define SCALE_PAM 0.04419417382415922f  // 1/sqrt(512)
#define SCALE_CAM (1.0f/64.0f)          // 1/sqrt(4096)
#define SHIFT_PAM 8.0f

typedef float v4f __attribute__((ext_vector_type(4)));
typedef short v8s __attribute__((ext_vector_type(8)));

__device__ __forceinline__ unsigned short f2bf(float f) {
  unsigned int u = __float_as_uint(f);
  u = (u + 0x7FFFu + ((u >> 16) & 1u)) >> 16;
  return (unsigned short)u;
}
__device__ __forceinline__ float bf2f(unsigned short s) {
  return __uint_as_float(((unsigned int)s) << 16);
}
__device__ __forceinline__ v8s ld8(const unsigned short* p) {
  v8s r; *(int4*)&r = *(const int4*)p; return r;
}
__device__ __forceinline__ v4f mfma16(v8s a, v8s b, v4f c) {
  return __builtin_amdgcn_mfma_f32_16x16x32_bf16(a, b, c, 0, 0, 0);
}
// PK layout: off(r,k) = ((r>>4)*(K>>5) + (k>>5))*512 + (r&15)*32 + (k&31)  [shorts]
// Wave frag load of block (r16,k32): base + lane_lin, lane_lin = (lane&15)*32+(lane>>4)*8
// -> one contiguous 1KB per wave.

// ---------------------------------------------------------------------------
// K_zero: zero acc (fp32 B*C*N) + l (fp32 B*N), contiguous region.
// ---------------------------------------------------------------------------
__global__ __launch_bounds__(256) void k_zero(float* __restrict__ p) {
  size_t i = ((size_t)blockIdx.x * 256 + threadIdx.x) * 4;
  *(float4*)(p + i) = (float4){0.f, 0.f, 0.f, 0.f};
}

// ---------------------------------------------------------------------------
// K_wb: wq/wk/wv fp32 -> w_pk PK(1024,512).
// ---------------------------------------------------------------------------
__global__ __launch_bounds__(256) void k_wb(const float* __restrict__ wq,
                                            const float* __restrict__ wk,
                                            const float* __restrict__ wv,
                                            unsigned short* __restrict__ w_pk) {
  int u = blockIdx.x * 256 + threadIdx.x;     // 65536 chunks
  int blk = u >> 6, wi = (u & 63) * 8;
  int r = (blk >> 4) * 16 + (wi >> 5);
  int k = (blk & 15) * 32 + (wi & 31);
  const float* src = (r < 256) ? &wq[r * 512 + k]
                   : (r < 512) ? &wk[(r - 256) * 512 + k]
                               : &wv[(r - 512) * 512 + k];
  float4 f0 = *(const float4*)src, f1 = *(const float4*)(src + 4);
  ushort4 o0 = { f2bf(f0.x), f2bf(f0.y), f2bf(f0.z), f2bf(f0.w) };
  ushort4 o1 = { f2bf(f1.x), f2bf(f1.y), f2bf(f1.z), f2bf(f1.w) };
  *(ushort4*)&w_pk[u * 8] = o0;
  *(ushort4*)&w_pk[u * 8 + 4] = o1;
}

// ---------------------------------------------------------------------------
// K_xT: x fp32 [b][c][n] -> x_pk PK(4096,512) per batch (rows n, cols c).
// ---------------------------------------------------------------------------
__global__ __launch_bounds__(256) void k_xT(const float* __restrict__ x,
                                            unsigned short* __restrict__ x_pk) {
  const int b = blockIdx.z, c0 = blockIdx.y * 64, n0 = blockIdx.x * 64;
  const int t = threadIdx.x;
  __shared__ unsigned short ts[64 * 72];  // [n][c]
  const int cl = t >> 2, nseg = (t & 3) * 16;
  const float* xr = x + ((size_t)b * C_ + c0 + cl) * N_ + n0 + nseg;
#pragma unroll
  for (int k = 0; k < 4; ++k) {
    float4 f = *(const float4*)(xr + k * 4);
    ts[(nseg + k * 4 + 0) * 72 + cl] = f2bf(f.x);
    ts[(nseg + k * 4 + 1) * 72 + cl] = f2bf(f.y);
    ts[(nseg + k * 4 + 2) * 72 + cl] = f2bf(f.z);
    ts[(nseg + k * 4 + 3) * 72 + cl] = f2bf(f.w);
  }
  __syncthreads();
  unsigned short* dst = x_pk + (size_t)b * N_ * C_;
#pragma unroll
  for (int u = t; u < 512; u += 256) {
    int blk = u >> 6, wi = (u & 63) * 8;
    int rl = (blk >> 1) * 16 + (wi >> 5);
    int kl = (blk & 1) * 32 + (wi & 31);
    int gr = n0 + rl, gk = c0 + kl;
    size_t go = ((size_t)(gr >> 4) * 16 + (gk >> 5)) * 512 + (gr & 15) * 32 + (gk & 31);
    *(int4*)&dst[go] = *(int4*)&ts[rl * 72 + kl];
  }
}

// ---------------------------------------------------------------------------
// K_qkv: y[o][n] = sum_c W[o][c] x[n][c] + b.  128o x 128n tile, 512 thr.
// A = w_pk frags, B = x_pk frags (both contiguous 1KB wave loads).
// q/k -> q_pk/k_pk PK(4096,256) (rows n, cols o) via LDS transpose;
// v -> v_pk PK(512,4096) (rows c, cols n) via LDS.
// ---------------------------------------------------------------------------
__global__ __launch_bounds__(512) void k_qkv(
    const unsigned short* __restrict__ w_pk, const unsigned short* __restrict__ x_pk,
    const float* __restrict__ bq, const float* __restrict__ bk, const float* __restrict__ bv,
    unsigned short* __restrict__ q_pk, unsigned short* __restrict__ k_pk,
    unsigned short* __restrict__ v_pk) {
  const int b = blockIdx.z, o0 = blockIdx.y * 128, n0 = blockIdx.x * 128;
  const int t = threadIdx.x, wave = t >> 6, lane = t & 63;
  const int la = lane & 15, quad = lane >> 4;
  const int ow = wave & 1, nw = wave >> 1;
  const int lanelin = la * 32 + quad * 8;
  const unsigned short* xpb = x_pk + (size_t)b * N_ * C_;
  __shared__ unsigned short tp[128 * 136];

  v4f acc[4][2];
#pragma unroll
  for (int i = 0; i < 4; ++i)
#pragma unroll
    for (int j = 0; j < 2; ++j) acc[i][j] = (v4f){0.f, 0.f, 0.f, 0.f};

  const int ar16 = (o0 + ow * 64) >> 4;        // w_pk row-blocks (K=512 -> 16 k32)
  const int br16 = (n0 + nw * 32) >> 4;        // x_pk row-blocks
#pragma unroll 4
  for (int s = 0; s < 16; ++s) {
    v8s b0 = ld8(&xpb[((size_t)(br16 + 0) * 16 + s) * 512 + lanelin]);
    v8s b1 = ld8(&xpb[((size_t)(br16 + 1) * 16 + s) * 512 + lanelin]);
#pragma unroll
    for (int oi = 0; oi < 4; ++oi) {
      v8s a = ld8(&w_pk[((size_t)(ar16 + oi) * 16 + s) * 512 + lanelin]);
      acc[oi][0] = mfma16(a, b0, acc[oi][0]);
      acc[oi][1] = mfma16(a, b1, acc[oi][1]);
    }
  }

  if (o0 >= 512) {
    // stage [c-local][n-local] then PK-write to v_pk
#pragma unroll
    for (int oi = 0; oi < 4; ++oi)
#pragma unroll
      for (int nj = 0; nj < 2; ++nj)
#pragma unroll
        for (int r = 0; r < 4; ++r) {
          int cl = ow * 64 + oi * 16 + quad * 4 + r;
          int nl = nw * 32 + nj * 16 + la;
          tp[cl * 136 + nl] = f2bf(acc[oi][nj][r] + bv[o0 - 512 + cl]);
        }
    __syncthreads();
    unsigned short* dst = v_pk + (size_t)b * C_ * N_;
#pragma unroll
    for (int u = t; u < 2048; u += 512) {
      int blk = u >> 6, wi = (u & 63) * 8;
      int rl = (blk >> 2) * 16 + (wi >> 5);
      int kl = (blk & 3) * 32 + (wi & 31);
      int gr = (o0 - 512) + rl, gk = n0 + kl;
      size_t go = ((size_t)(gr >> 4) * 128 + (gk >> 5)) * 512 + (gr & 15) * 32 + (gk & 31);
      *(int4*)&dst[go] = *(int4*)&tp[rl * 136 + kl];
    }
  } else {
    const float* bias = (o0 < 256) ? bq : bk;
#pragma unroll
    for (int oi = 0; oi < 4; ++oi)
#pragma unroll
      for (int nj = 0; nj < 2; ++nj)
#pragma unroll
        for (int r = 0; r < 4; ++r) {
          int ol = ow * 64 + oi * 16 + quad * 4 + r;
          int nl = nw * 32 + nj * 16 + la;
          tp[nl * 136 + ol] = f2bf(acc[oi][nj][r] + bias[(o0 & 255) + ol]);
        }
    __syncthreads();
    unsigned short* dst = ((o0 < 256) ? q_pk : k_pk) + (size_t)b * N_ * CI_;
#pragma unroll
    for (int u = t; u < 2048; u += 512) {
      int blk = u >> 6, wi = (u & 63) * 8;
      int rl = (blk >> 2) * 16 + (wi >> 5);
      int kl = (blk & 3) * 32 + (wi & 31);
      int gr = n0 + rl, gk = (o0 & 255) + kl;
      size_t go = ((size_t)(gr >> 4) * 8 + (gk >> 5)) * 512 + (gr & 15) * 32 + (gk & 31);
      *(int4*)&dst[go] = *(int4*)&tp[rl * 136 + kl];
    }
  }
}

// ---------------------------------------------------------------------------
// K_pam: fixed-shift flash, i-tile 64, j-half per block (XCD-swizzled).
// grid 512 (1-D): xcd=blk&7 -> (b=xcd>>1, jh=xcd&1), i0=(blk>>3)*64.
// 8 waves: S: (iw=w&3, jw=w>>2) 16x16 subtile of 64i x 32j; PV: c=[w*64,+64).
// Partial acc/l -> global fp32 atomicAdd.
// ---------------------------------------------------------------------------
__global__ __launch_bounds__(512, 2) void k_pam(
    const unsigned short* __restrict__ q_pk, const unsigned short* __restrict__ k_pk,
    const unsigned short* __restrict__ v_pk,
    float* __restrict__ acc_g, float* __restrict__ l_g) {
  const int blk = blockIdx.x;
  const int b = (blk & 7) >> 1, jh = blk & 1, i0 = (blk >> 3) * 64;
  const int t = threadIdx.x, wave = t >> 6, lane = t & 63;
  const int la = lane & 15, quad = lane >> 4;
  const int iw = wave & 3, jw = wave >> 2;
  const int cb = wave * 64;
  const int lanelin = la * 32 + quad * 8;

  __shared__ unsigned short pa[2][64 * 40];
  __shared__ float l_lds[64];
  if (t < 64) l_lds[t] = 0.f;

  const unsigned short* qpk = q_pk + (size_t)b * N_ * CI_;
  const unsigned short* kpk = k_pk + (size_t)b * N_ * CI_;
  const unsigned short* vpk = v_pk + (size_t)b * C_ * N_;

  v8s qf[8];
  {
    const unsigned short* qb = qpk + ((size_t)((i0 >> 4) + iw) * 8) * 512 + lanelin;
#pragma unroll
    for (int s = 0; s < 8; ++s) qf[s] = ld8(qb + s * 512);
  }

  v4f acc[4][4];
#pragma unroll
  for (int ct = 0; ct < 4; ++ct)
#pragma unroll
    for (int it = 0; it < 4; ++it) acc[ct][it] = (v4f){0.f, 0.f, 0.f, 0.f};
  float lsum[4] = {0.f, 0.f, 0.f, 0.f};

  int buf = 0;
  const int jbeg = jh * 2048, jend = jbeg + 2048;
  for (int j0 = jbeg; j0 < jend; j0 += 32) {
    // S = Q K^T (split-K, 2 chains)
    const unsigned short* kb = kpk + ((size_t)((j0 >> 4) + jw) * 8) * 512 + lanelin;
    v4f sA = (v4f){0.f, 0.f, 0.f, 0.f}, sB = sA;
#pragma unroll
    for (int sh = 0; sh < 4; ++sh) {
      sA = mfma16(qf[sh], ld8(kb + sh * 512), sA);
      sB = mfma16(qf[sh + 4], ld8(kb + (sh + 4) * 512), sB);
    }
    // V frags for this j-tile (1 k32 chunk)
    v8s vf[4];
#pragma unroll
    for (int ct = 0; ct < 4; ++ct)
      vf[ct] = ld8(&vpk[((size_t)((cb >> 4) + ct) * 128 + (j0 >> 5)) * 512 + lanelin]);
    // P = exp(s*scale - shift)
#pragma unroll
    for (int r = 0; r < 4; ++r) {
      float p = __expf((sA[r] + sB[r]) * SCALE_PAM - SHIFT_PAM);
      lsum[r] += p;
      pa[buf][(iw * 16 + quad * 4 + r) * 40 + jw * 16 + la] = f2bf(p);
    }
    __syncthreads();
    // PV: acc[c][i] += V[c][j] * P[i][j]
#pragma unroll
    for (int it = 0; it < 4; ++it) {
      v8s pf; *(int4*)&pf = *(const int4*)&pa[buf][(it * 16 + la) * 40 + quad * 8];
#pragma unroll
      for (int ct = 0; ct < 4; ++ct)
        acc[ct][it] = mfma16(vf[ct], pf, acc[ct][it]);
    }
    buf ^= 1;
  }

#pragma unroll
  for (int r = 0; r < 4; ++r) {
    float v = lsum[r];
    v += __shfl_xor(v, 1); v += __shfl_xor(v, 2);
    v += __shfl_xor(v, 4); v += __shfl_xor(v, 8);
    if (la == 0) atomicAdd(&l_lds[iw * 16 + quad * 4 + r], v);
  }
  __syncthreads();
  if (t < 64) atomicAdd(&l_g[(size_t)b * N_ + i0 + t], l_lds[t]);

  float* accb = acc_g + (size_t)b * C_ * N_;
#pragma unroll
  for (int ct = 0; ct < 4; ++ct)
#pragma unroll
    for (int it = 0; it < 4; ++it)
#pragma unroll
      for (int r = 0; r < 4; ++r)
        atomicAdd(&accb[(size_t)(cb + ct * 16 + quad * 4 + r) * N_ + i0 + it * 16 + la],
                  acc[ct][it][r]);
}

// ---------------------------------------------------------------------------
// K_combine: sa = tanh(gp*acc/(l*N) + x); emit sa_pk PK(512,4096) and
// saT_pk PK(4096,512). 64c x 64n tile, 256 thr.
// ---------------------------------------------------------------------------
__global__ __launch_bounds__(256) void k_combine(
    const float* __restrict__ acc_g, const float* __restrict__ l_g,
    const float* __restrict__ x, const float* __restrict__ gamma_pam,
    unsigned short* __restrict__ sa_pk, unsigned short* __restrict__ saT_pk) {
  const int b = blockIdx.z, c0 = blockIdx.y * 64, n0 = blockIdx.x * 64;
  const int t = threadIdx.x;
  const int cl = t >> 2, nseg = (t & 3) * 16;
  __shared__ unsigned short ts[64 * 72];
  const float gpv = gamma_pam[0];
  const float* ar = acc_g + ((size_t)b * C_ + c0 + cl) * N_ + n0 + nseg;
  const float* xr = x + ((size_t)b * C_ + c0 + cl) * N_ + n0 + nseg;
  const float* lr = l_g + (size_t)b * N_ + n0 + nseg;
  unsigned short sv[16];
#pragma unroll
  for (int k = 0; k < 4; ++k) {
    float4 a4 = *(const float4*)(ar + k * 4);
    float4 x4 = *(const float4*)(xr + k * 4);
    float4 l4 = *(const float4*)(lr + k * 4);
    sv[k * 4 + 0] = f2bf(tanhf(fmaf(gpv, a4.x / (l4.x * (float)N_), x4.x)));
    sv[k * 4 + 1] = f2bf(tanhf(fmaf(gpv, a4.y / (l4.y * (float)N_), x4.y)));
    sv[k * 4 + 2] = f2bf(tanhf(fmaf(gpv, a4.z / (l4.z * (float)N_), x4.z)));
    sv[k * 4 + 3] = f2bf(tanhf(fmaf(gpv, a4.w / (l4.w * (float)N_), x4.w)));
  }
  // stage [c][n] -> sa_pk
#pragma unroll
  for (int k = 0; k < 16; ++k) ts[cl * 72 + nseg + k] = sv[k];
  __syncthreads();
  {
    unsigned short* dst = sa_pk + (size_t)b * C_ * N_;
#pragma unroll
    for (int u = t; u < 512; u += 256) {
      int blk = u >> 6, wi = (u & 63) * 8;
      int rl = (blk >> 1) * 16 + (wi >> 5);
      int kl = (blk & 1) * 32 + (wi & 31);
      int gr = c0 + rl, gk = n0 + kl;
      size_t go = ((size_t)(gr >> 4) * 128 + (gk >> 5)) * 512 + (gr & 15) * 32 + (gk & 31);
      *(int4*)&dst[go] = *(int4*)&ts[rl * 72 + kl];
    }
  }
  __syncthreads();
  // stage [n][c] -> saT_pk
#pragma unroll
  for (int k = 0; k < 16; ++k) ts[(nseg + k) * 72 + cl] = sv[k];
  __syncthreads();
  {
    unsigned short* dst = saT_pk + (size_t)b * N_ * C_;
#pragma unroll
    for (int u = t; u < 512; u += 256) {
      int blk = u >> 6, wi = (u & 63) * 8;
      int rl = (blk >> 1) * 16 + (wi >> 5);
      int kl = (blk & 1) * 32 + (wi & 31);
      int gr = n0 + rl, gk = c0 + kl;
      size_t go = ((size_t)(gr >> 4) * 16 + (gk >> 5)) * 512 + (gr & 15) * 32 + (gk & 31);
      *(int4*)&dst[go] = *(int4*)&ts[rl * 72 + kl];
    }
  }
}

// ---------------------------------------------------------------------------
// K_cam_e: e_part[ks][b][c][d] = scale * sum_n sa_c sa_d.  64x64 tile, ks4.
// ---------------------------------------------------------------------------
__global__ __launch_bounds__(256) void k_cam_e(const unsigned short* __restrict__ sa_pk,
                                               float* __restrict__ e_part) {
  const int b = blockIdx.z, ks = blockIdx.y;
  const int c0 = (blockIdx.x & 7) * 64, d0 = (blockIdx.x >> 3) * 64;
  const int t = threadIdx.x, wave = t >> 6, lane = t & 63;
  const int la = lane & 15, quad = lane >> 4;
  const int cw = wave & 1, dw = wave >> 1;
  const int lanelin = la * 32 + quad * 8;
  const unsigned short* sb = sa_pk + (size_t)b * C_ * N_;

  v4f acc[2][2];
#pragma unroll
  for (int i = 0; i < 2; ++i)
#pragma unroll
    for (int j = 0; j < 2; ++j) acc[i][j] = (v4f){0.f, 0.f, 0.f, 0.f};

  const int ar16 = (c0 + cw * 32) >> 4;
  const int br16 = (d0 + dw * 32) >> 4;
#pragma unroll 4
  for (int s = 0; s < 32; ++s) {
    const int k32 = ks * 32 + s;
    v8s a0 = ld8(&sb[((size_t)(ar16 + 0) * 128 + k32) * 512 + lanelin]);
    v8s a1 = ld8(&sb[((size_t)(ar16 + 1) * 128 + k32) * 512 + lanelin]);
    v8s b0 = ld8(&sb[((size_t)(br16 + 0) * 128 + k32) * 512 + lanelin]);
    v8s b1 = ld8(&sb[((size_t)(br16 + 1) * 128 + k32) * 512 + lanelin]);
    acc[0][0] = mfma16(a0, b0, acc[0][0]);
    acc[0][1] = mfma16(a0, b1, acc[0][1]);
    acc[1][0] = mfma16(a1, b0, acc[1][0]);
    acc[1][1] = mfma16(a1, b1, acc[1][1]);
  }
  float* ep = e_part + ((size_t)(ks * B_ + b)) * C_ * C_;
#pragma unroll
  for (int i = 0; i < 2; ++i)
#pragma unroll
    for (int j = 0; j < 2; ++j)
#pragma unroll
      for (int r = 0; r < 4; ++r) {
        int c = c0 + cw * 32 + i * 16 + quad * 4 + r;
        int d = d0 + dw * 32 + j * 16 + la;
        ep[(size_t)c * C_ + d] = acc[i][j][r] * SCALE_CAM;
      }
}

// ---------------------------------------------------------------------------
// K_cam_softmax: min-trick softmax over 4 parts -> attn_pk PK(512,512).
// ---------------------------------------------------------------------------
__global__ __launch_bounds__(64) void k_cam_softmax(const float* __restrict__ e_part,
                                                    unsigned short* __restrict__ attn_pk) {
  const int c = blockIdx.x, b = blockIdx.y, lane = threadIdx.x;
  size_t roff = ((size_t)b * C_ + c) * C_;
  float vals[8];
#pragma unroll
  for (int r = 0; r < 8; ++r) {
    int d = lane + r * 64;
    float s = 0.f;
#pragma unroll
    for (int p = 0; p < 4; ++p) s += e_part[(size_t)(p * B_) * C_ * C_ + roff + d];
    vals[r] = s;
  }
  float mn = vals[0];
#pragma unroll
  for (int r = 1; r < 8; ++r) mn = fminf(mn, vals[r]);
#pragma unroll
  for (int m = 32; m >= 1; m >>= 1) mn = fminf(mn, __shfl_xor(mn, m));
  float sum = 0.f;
#pragma unroll
  for (int r = 0; r < 8; ++r) { vals[r] = __expf(mn - vals[r]); sum += vals[r]; }
#pragma unroll
  for (int m = 32; m >= 1; m >>= 1) sum += __shfl_xor(sum, m);
  float sc = (1.0f / (float)C_) / sum;
  unsigned short* ab = attn_pk + (size_t)b * C_ * C_;
#pragma unroll
  for (int r = 0; r < 8; ++r) {
    int d = lane + r * 64;
    size_t go = ((size_t)(c >> 4) * 16 + (d >> 5)) * 512 + (c & 15) * 32 + (d & 31);
    ab[go] = f2bf(vals[r] * sc);
  }
}

// ---------------------------------------------------------------------------
// K_cam_out: out = gc * (attn @ sa) + sa.  128c x 128n tile, 512 thr.
// A = attn_pk, B = saT_pk; residual from sa_pk.
// ---------------------------------------------------------------------------
__global__ __launch_bounds__(512) void k_cam_out(
    const unsigned short* __restrict__ attn_pk, const unsigned short* __restrict__ saT_pk,
    const unsigned short* __restrict__ sa_pk, const float* __restrict__ gamma_cam,
    float* __restrict__ out) {
  const int b = blockIdx.z, c0 = blockIdx.y * 128, n0 = blockIdx.x * 128;
  const int t = threadIdx.x, wave = t >> 6, lane = t & 63;
  const int la = lane & 15, quad = lane >> 4;
  const int cw = wave & 1, nw = wave >> 1;
  const int lanelin = la * 32 + quad * 8;
  const unsigned short* ab = attn_pk + (size_t)b * C_ * C_;
  const unsigned short* sTb = saT_pk + (size_t)b * N_ * C_;
  const unsigned short* sb = sa_pk + (size_t)b * C_ * N_;

  v4f acc[4][2];
#pragma unroll
  for (int i = 0; i < 4; ++i)
#pragma unroll
    for (int j = 0; j < 2; ++j) acc[i][j] = (v4f){0.f, 0.f, 0.f, 0.f};

  const int ar16 = (c0 + cw * 64) >> 4;
  const int br16 = (n0 + nw * 32) >> 4;
#pragma unroll 4
  for (int s = 0; s < 16; ++s) {
    v8s b0 = ld8(&sTb[((size_t)(br16 + 0) * 16 + s) * 512 + lanelin]);
    v8s b1 = ld8(&sTb[((size_t)(br16 + 1) * 16 + s) * 512 + lanelin]);
#pragma unroll
    for (int ci = 0; ci < 4; ++ci) {
      v8s a = ld8(&ab[((size_t)(ar16 + ci) * 16 + s) * 512 + lanelin]);
      acc[ci][0] = mfma16(a, b0, acc[ci][0]);
      acc[ci][1] = mfma16(a, b1, acc[ci][1]);
    }
  }
  const float gc = gamma_cam[0];
#pragma unroll
  for (int ci = 0; ci < 4; ++ci)
#pragma unroll
    for (int nj = 0; nj < 2; ++nj)
#pragma unroll
      for (int r = 0; r < 4; ++r) {
        int c = c0 + cw * 64 + ci * 16 + quad * 4 + r;
        int n = n0 + nw * 32 + nj * 16 + la;
        size_t pko = ((size_t)(c >> 4) * 128 + (n >> 5)) * 512 + (c & 15) * 32 + (n & 31);
        out[((size_t)b * C_ + c) * N_ + n] = fmaf(gc, acc[ci][nj][r], bf2f(sb[pko]));
      }
}

// ---------------------------------------------------------------------------
extern "C" void kernel_launch(void* const* d_in, const int* in_sizes, int n_in,
                              void* d_out, int out_size, void* d_ws, size_t ws_size,
                              hipStream_t stream) {
  const float* x  = (const float*)d_in[0];
  const float* wq = (const float*)d_in[1];
  const float* bq = (const float*)d_in[2];
  const float* wk = (const float*)d_in[3];
  const float* bk = (const float*)d_in[4];
  const float* wv = (const float*)d_in[5];
  const float* bv = (const float*)d_in[6];
  const float* gp = (const float*)d_in[7];
  const float* gc = (const float*)d_in[8];
  float* out = (float*)d_out;

  char* ws = (char*)d_ws;
  unsigned short* x_pk   = (unsigned short*)(ws);              // 16.78 MB
  unsigned short* w_pk   = (unsigned short*)(ws + 16777216);   // 1.05 MB
  unsigned short* q_pk   = (unsigned short*)(ws + 17825792);   // 8.39 MB
  unsigned short* k_pk   = (unsigned short*)(ws + 26214400);   // 8.39 MB
  unsigned short* v_pk   = (unsigned short*)(ws + 34603008);   // 16.78 MB
  float*          acc_g  = (float*)(ws + 51380224);            // 33.55 MB
  float*          l_g    = (float*)(ws + 84934656);            // 64 KB
  unsigned short* sa_pk  = (unsigned short*)(ws + 85000192);   // 16.78 MB
  unsigned short* saT_pk = (unsigned short*)(ws + 101777408);  // 16.78 MB
  float*          ep     = (float*)(ws + 118554624);           // 16.78 MB
  unsigned short* at_pk  = (unsigned short*)(ws + 135331840);  // 2.10 MB
  // total ~137.4 MB

  k_zero<<<8208, 256, 0, stream>>>(acc_g);                       // acc + l contiguous
  k_xT<<<dim3(64, 8, B_), 256, 0, stream>>>(x, x_pk);
  k_wb<<<256, 256, 0, stream>>>(wq, wk, wv, w_pk);
  k_qkv<<<dim3(32, 8, B_), 512, 0, stream>>>(w_pk, x_pk, bq, bk, bv, q_pk, k_pk, v_pk);
  k_pam<<<512, 512, 0, stream>>>(q_pk, k_pk, v_pk, acc_g, l_g);
  k_combine<<<dim3(64, 8, B_), 256, 0, stream>>>(acc_g, l_g, x, gp, sa_pk, saT_pk);
  k_cam_e<<<dim3(64, 4, B_), 256, 0, stream>>>(sa_pk, ep);
  k_cam_softmax<<<dim3(C_, B_), 64, 0, stream>>>(ep, at_pk);
  k_cam_out<<<dim3(32, 4, B_), 512, 0, stream>>>(at_pk, saT_pk, sa_pk, gc, out);
}

// Round 6
// 463.925 us; speedup vs baseline: 1.6544x; 1.0447x over previous
//
#include <hip/hip_runtime.h>

#define B_ 4
#define C_ 512
#define CI_ 256
#define N_ 4096
#define SCALE_PAM 0.04419417382415922f  // 1/sqrt(512)
#define SCALE_CAM (1.0f/64.0f)          // 1/sqrt(4096)
#define SHIFT_PAM 8.0f

typedef float v4f __attribute__((ext_vector_type(4)));
typedef short v8s __attribute__((ext_vector_type(8)));

__device__ __forceinline__ unsigned short f2bf(float f) {
  unsigned int u = __float_as_uint(f);
  u = (u + 0x7FFFu + ((u >> 16) & 1u)) >> 16;
  return (unsigned short)u;
}
__device__ __forceinline__ float bf2f(unsigned short s) {
  return __uint_as_float(((unsigned int)s) << 16);
}
__device__ __forceinline__ v8s ld8(const unsigned short* p) {
  v8s r; *(int4*)&r = *(const int4*)p; return r;
}
__device__ __forceinline__ v4f mfma16(v8s a, v8s b, v4f c) {
  return __builtin_amdgcn_mfma_f32_16x16x32_bf16(a, b, c, 0, 0, 0);
}
// PK layout: off(r,k) = ((r>>4)*(K>>5) + (k>>5))*512 + (r&15)*32 + (k&31)  [shorts]
// Wave frag load: base + lanelin, lanelin=(lane&15)*32+(lane>>4)*8 -> contiguous 1KB.

// ---------------------------------------------------------------------------
// K_wb: wq/wk/wv fp32 -> w_pk PK(1024,512).
// ---------------------------------------------------------------------------
__global__ __launch_bounds__(256) void k_wb(const float* __restrict__ wq,
                                            const float* __restrict__ wk,
                                            const float* __restrict__ wv,
                                            unsigned short* __restrict__ w_pk) {
  int u = blockIdx.x * 256 + threadIdx.x;
  int blk = u >> 6, wi = (u & 63) * 8;
  int r = (blk >> 4) * 16 + (wi >> 5);
  int k = (blk & 15) * 32 + (wi & 31);
  const float* src = (r < 256) ? &wq[r * 512 + k]
                   : (r < 512) ? &wk[(r - 256) * 512 + k]
                               : &wv[(r - 512) * 512 + k];
  float4 f0 = *(const float4*)src, f1 = *(const float4*)(src + 4);
  ushort4 o0 = { f2bf(f0.x), f2bf(f0.y), f2bf(f0.z), f2bf(f0.w) };
  ushort4 o1 = { f2bf(f1.x), f2bf(f1.y), f2bf(f1.z), f2bf(f1.w) };
  *(ushort4*)&w_pk[u * 8] = o0;
  *(ushort4*)&w_pk[u * 8 + 4] = o1;
}

// ---------------------------------------------------------------------------
// K_xT: x fp32 [b][c][n] -> x_pk PK(4096,512) per batch (rows n, cols c).
// ---------------------------------------------------------------------------
__global__ __launch_bounds__(256) void k_xT(const float* __restrict__ x,
                                            unsigned short* __restrict__ x_pk) {
  const int b = blockIdx.z, c0 = blockIdx.y * 64, n0 = blockIdx.x * 64;
  const int t = threadIdx.x;
  __shared__ unsigned short ts[64 * 72];  // [n][c]
  const int cl = t >> 2, nseg = (t & 3) * 16;
  const float* xr = x + ((size_t)b * C_ + c0 + cl) * N_ + n0 + nseg;
#pragma unroll
  for (int k = 0; k < 4; ++k) {
    float4 f = *(const float4*)(xr + k * 4);
    ts[(nseg + k * 4 + 0) * 72 + cl] = f2bf(f.x);
    ts[(nseg + k * 4 + 1) * 72 + cl] = f2bf(f.y);
    ts[(nseg + k * 4 + 2) * 72 + cl] = f2bf(f.z);
    ts[(nseg + k * 4 + 3) * 72 + cl] = f2bf(f.w);
  }
  __syncthreads();
  unsigned short* dst = x_pk + (size_t)b * N_ * C_;
#pragma unroll
  for (int u = t; u < 512; u += 256) {
    int blk = u >> 6, wi = (u & 63) * 8;
    int rl = (blk >> 1) * 16 + (wi >> 5);
    int kl = (blk & 1) * 32 + (wi & 31);
    int gr = n0 + rl, gk = c0 + kl;
    size_t go = ((size_t)(gr >> 4) * 16 + (gk >> 5)) * 512 + (gr & 15) * 32 + (gk & 31);
    *(int4*)&dst[go] = *(int4*)&ts[rl * 72 + kl];
  }
}

// ---------------------------------------------------------------------------
// K_qkv: y[o][n] = sum_c W[o][c] x[n][c] + b.  128o x 128n tile, 512 thr.
// ---------------------------------------------------------------------------
__global__ __launch_bounds__(512) void k_qkv(
    const unsigned short* __restrict__ w_pk, const unsigned short* __restrict__ x_pk,
    const float* __restrict__ bq, const float* __restrict__ bk, const float* __restrict__ bv,
    unsigned short* __restrict__ q_pk, unsigned short* __restrict__ k_pk,
    unsigned short* __restrict__ v_pk) {
  const int b = blockIdx.z, o0 = blockIdx.y * 128, n0 = blockIdx.x * 128;
  const int t = threadIdx.x, wave = t >> 6, lane = t & 63;
  const int la = lane & 15, quad = lane >> 4;
  const int ow = wave & 1, nw = wave >> 1;
  const int lanelin = la * 32 + quad * 8;
  const unsigned short* xpb = x_pk + (size_t)b * N_ * C_;
  __shared__ unsigned short tp[128 * 136];

  v4f acc[4][2];
#pragma unroll
  for (int i = 0; i < 4; ++i)
#pragma unroll
    for (int j = 0; j < 2; ++j) acc[i][j] = (v4f){0.f, 0.f, 0.f, 0.f};

  const int ar16 = (o0 + ow * 64) >> 4;
  const int br16 = (n0 + nw * 32) >> 4;
#pragma unroll 4
  for (int s = 0; s < 16; ++s) {
    v8s b0 = ld8(&xpb[((size_t)(br16 + 0) * 16 + s) * 512 + lanelin]);
    v8s b1 = ld8(&xpb[((size_t)(br16 + 1) * 16 + s) * 512 + lanelin]);
#pragma unroll
    for (int oi = 0; oi < 4; ++oi) {
      v8s a = ld8(&w_pk[((size_t)(ar16 + oi) * 16 + s) * 512 + lanelin]);
      acc[oi][0] = mfma16(a, b0, acc[oi][0]);
      acc[oi][1] = mfma16(a, b1, acc[oi][1]);
    }
  }

  if (o0 >= 512) {
#pragma unroll
    for (int oi = 0; oi < 4; ++oi)
#pragma unroll
      for (int nj = 0; nj < 2; ++nj)
#pragma unroll
        for (int r = 0; r < 4; ++r) {
          int cl = ow * 64 + oi * 16 + quad * 4 + r;
          int nl = nw * 32 + nj * 16 + la;
          tp[cl * 136 + nl] = f2bf(acc[oi][nj][r] + bv[o0 - 512 + cl]);
        }
    __syncthreads();
    unsigned short* dst = v_pk + (size_t)b * C_ * N_;
#pragma unroll
    for (int u = t; u < 2048; u += 512) {
      int blk = u >> 6, wi = (u & 63) * 8;
      int rl = (blk >> 2) * 16 + (wi >> 5);
      int kl = (blk & 3) * 32 + (wi & 31);
      int gr = (o0 - 512) + rl, gk = n0 + kl;
      size_t go = ((size_t)(gr >> 4) * 128 + (gk >> 5)) * 512 + (gr & 15) * 32 + (gk & 31);
      *(int4*)&dst[go] = *(int4*)&tp[rl * 136 + kl];
    }
  } else {
    const float* bias = (o0 < 256) ? bq : bk;
#pragma unroll
    for (int oi = 0; oi < 4; ++oi)
#pragma unroll
      for (int nj = 0; nj < 2; ++nj)
#pragma unroll
        for (int r = 0; r < 4; ++r) {
          int ol = ow * 64 + oi * 16 + quad * 4 + r;
          int nl = nw * 32 + nj * 16 + la;
          tp[nl * 136 + ol] = f2bf(acc[oi][nj][r] + bias[(o0 & 255) + ol]);
        }
    __syncthreads();
    unsigned short* dst = ((o0 < 256) ? q_pk : k_pk) + (size_t)b * N_ * CI_;
#pragma unroll
    for (int u = t; u < 2048; u += 512) {
      int blk = u >> 6, wi = (u & 63) * 8;
      int rl = (blk >> 2) * 16 + (wi >> 5);
      int kl = (blk & 3) * 32 + (wi & 31);
      int gr = n0 + rl, gk = (o0 & 255) + kl;
      size_t go = ((size_t)(gr >> 4) * 8 + (gk >> 5)) * 512 + (gr & 15) * 32 + (gk & 31);
      *(int4*)&dst[go] = *(int4*)&tp[rl * 136 + kl];
    }
  }
}

// ---------------------------------------------------------------------------
// K_pam v6: fixed-shift flash. 1024 thr (16 waves), i-tile 64, j-tile 64/iter,
// jh-split + XCD swizzle: blk&7 -> (b, jh); i0 = (blk>>3)*64. Grid 512.
// S: wave w -> subtile (iw=w&3, jw=w>>2), 2 split-K chains.
// PV: c-split 16 ways x 32 channels -> acc only 32 VGPR/lane.
// One barrier per iter (double-buffered P, stride 66 = ~2-way-conflict b128).
// Partials -> per-jh slabs with PLAIN stores (no atomics, no zeroing).
// ---------------------------------------------------------------------------
__global__ __launch_bounds__(1024) void k_pam(
    const unsigned short* __restrict__ q_pk, const unsigned short* __restrict__ k_pk,
    const unsigned short* __restrict__ v_pk,
    float* __restrict__ acc_part, float* __restrict__ l_part) {
  const int blk = blockIdx.x;
  const int b = (blk & 7) >> 1, jh = blk & 1, i0 = (blk >> 3) * 64;
  const int t = threadIdx.x, wave = t >> 6, lane = t & 63;
  const int la = lane & 15, quad = lane >> 4;
  const int iw = wave & 3, jw = wave >> 2;
  const int cb = wave * 32;
  const int lanelin = la * 32 + quad * 8;

  __shared__ unsigned short pa[2][64 * 66];
  __shared__ float l_lds[64];
  if (t < 64) l_lds[t] = 0.f;

  const unsigned short* qpk = q_pk + (size_t)b * N_ * CI_;
  const unsigned short* kpk = k_pk + (size_t)b * N_ * CI_;
  const unsigned short* vpk = v_pk + (size_t)b * C_ * N_;

  v8s qf[8];
  {
    const unsigned short* qb = qpk + ((size_t)((i0 >> 4) + iw) * 8) * 512 + lanelin;
#pragma unroll
    for (int s = 0; s < 8; ++s) qf[s] = ld8(qb + s * 512);
  }

  v4f acc[2][4];  // [ct][it]
#pragma unroll
  for (int ct = 0; ct < 2; ++ct)
#pragma unroll
    for (int it = 0; it < 4; ++it) acc[ct][it] = (v4f){0.f, 0.f, 0.f, 0.f};
  float lsum[4] = {0.f, 0.f, 0.f, 0.f};

  int buf = 0;
  const int jbeg = jh * 2048, jend = jbeg + 2048;
  for (int j0 = jbeg; j0 < jend; j0 += 64) {
    // K frags for this wave's j-subtile (consumed first -> issue first)
    const unsigned short* kb = kpk + ((size_t)((j0 >> 4) + jw) * 8) * 512 + lanelin;
    // V frags (consumed after barrier; issued early to hide L2 latency)
    v8s vf[2][2];
#pragma unroll
    for (int ct = 0; ct < 2; ++ct)
#pragma unroll
      for (int ks = 0; ks < 2; ++ks)
        vf[ct][ks] = ld8(&vpk[((size_t)((cb >> 4) + ct) * 128 + (j0 >> 5) + ks) * 512 + lanelin]);
    // S = Q K^T (2 independent chains)
    v4f sA = (v4f){0.f, 0.f, 0.f, 0.f}, sB = sA;
#pragma unroll
    for (int sh = 0; sh < 4; ++sh) {
      sA = mfma16(qf[sh], ld8(kb + sh * 512), sA);
      sB = mfma16(qf[sh + 4], ld8(kb + (sh + 4) * 512), sB);
    }
    // P = exp(s*scale - shift)
#pragma unroll
    for (int r = 0; r < 4; ++r) {
      float p = __expf((sA[r] + sB[r]) * SCALE_PAM - SHIFT_PAM);
      lsum[r] += p;
      pa[buf][(iw * 16 + quad * 4 + r) * 66 + jw * 16 + la] = f2bf(p);
    }
    __syncthreads();
    // PV: acc[c][i] += V[c][j] * P[i][j]
#pragma unroll
    for (int it = 0; it < 4; ++it)
#pragma unroll
      for (int ks = 0; ks < 2; ++ks) {
        v8s pf; *(int4*)&pf = *(const int4*)&pa[buf][(it * 16 + la) * 66 + ks * 32 + quad * 8];
#pragma unroll
        for (int ct = 0; ct < 2; ++ct)
          acc[ct][it] = mfma16(vf[ct][ks], pf, acc[ct][it]);
      }
    buf ^= 1;
  }

  // reduce l per i-row (la lanes within quad, then 4 jw waves via LDS atomic)
#pragma unroll
  for (int r = 0; r < 4; ++r) {
    float v = lsum[r];
    v += __shfl_xor(v, 1); v += __shfl_xor(v, 2);
    v += __shfl_xor(v, 4); v += __shfl_xor(v, 8);
    if (la == 0) atomicAdd(&l_lds[iw * 16 + quad * 4 + r], v);
  }
  __syncthreads();
  if (t < 64) l_part[((size_t)jh * B_ + b) * N_ + i0 + t] = l_lds[t];

  float* ap = acc_part + ((size_t)jh * B_ + b) * C_ * N_;
#pragma unroll
  for (int ct = 0; ct < 2; ++ct)
#pragma unroll
    for (int it = 0; it < 4; ++it)
#pragma unroll
      for (int r = 0; r < 4; ++r)
        ap[(size_t)(cb + ct * 16 + quad * 4 + r) * N_ + i0 + it * 16 + la] = acc[ct][it][r];
}

// ---------------------------------------------------------------------------
// K_combine: sa = tanh(gp*(a0+a1)/((l0+l1)*N) + x); emit sa_pk + saT_pk.
// ---------------------------------------------------------------------------
__global__ __launch_bounds__(256) void k_combine(
    const float* __restrict__ acc_part, const float* __restrict__ l_part,
    const float* __restrict__ x, const float* __restrict__ gamma_pam,
    unsigned short* __restrict__ sa_pk, unsigned short* __restrict__ saT_pk) {
  const int b = blockIdx.z, c0 = blockIdx.y * 64, n0 = blockIdx.x * 64;
  const int t = threadIdx.x;
  const int cl = t >> 2, nseg = (t & 3) * 16;
  __shared__ unsigned short ts[64 * 72];
  const float gpv = gamma_pam[0];
  const size_t rowoff = ((size_t)b * C_ + c0 + cl) * N_ + n0 + nseg;
  const float* a0 = acc_part + rowoff;
  const float* a1 = acc_part + (size_t)B_ * C_ * N_ + rowoff;
  const float* xr = x + rowoff;
  const float* l0 = l_part + (size_t)b * N_ + n0 + nseg;
  const float* l1 = l_part + ((size_t)B_ + b) * N_ + n0 + nseg;
  unsigned short sv[16];
#pragma unroll
  for (int k = 0; k < 4; ++k) {
    float4 p4 = *(const float4*)(a0 + k * 4);
    float4 q4 = *(const float4*)(a1 + k * 4);
    float4 x4 = *(const float4*)(xr + k * 4);
    float4 u4 = *(const float4*)(l0 + k * 4);
    float4 w4 = *(const float4*)(l1 + k * 4);
    sv[k * 4 + 0] = f2bf(tanhf(fmaf(gpv, (p4.x + q4.x) / ((u4.x + w4.x) * (float)N_), x4.x)));
    sv[k * 4 + 1] = f2bf(tanhf(fmaf(gpv, (p4.y + q4.y) / ((u4.y + w4.y) * (float)N_), x4.y)));
    sv[k * 4 + 2] = f2bf(tanhf(fmaf(gpv, (p4.z + q4.z) / ((u4.z + w4.z) * (float)N_), x4.z)));
    sv[k * 4 + 3] = f2bf(tanhf(fmaf(gpv, (p4.w + q4.w) / ((u4.w + w4.w) * (float)N_), x4.w)));
  }
  // stage [c][n] -> sa_pk
#pragma unroll
  for (int k = 0; k < 16; ++k) ts[cl * 72 + nseg + k] = sv[k];
  __syncthreads();
  {
    unsigned short* dst = sa_pk + (size_t)b * C_ * N_;
#pragma unroll
    for (int u = t; u < 512; u += 256) {
      int blk = u >> 6, wi = (u & 63) * 8;
      int rl = (blk >> 1) * 16 + (wi >> 5);
      int kl = (blk & 1) * 32 + (wi & 31);
      int gr = c0 + rl, gk = n0 + kl;
      size_t go = ((size_t)(gr >> 4) * 128 + (gk >> 5)) * 512 + (gr & 15) * 32 + (gk & 31);
      *(int4*)&dst[go] = *(int4*)&ts[rl * 72 + kl];
    }
  }
  __syncthreads();
  // stage [n][c] -> saT_pk
#pragma unroll
  for (int k = 0; k < 16; ++k) ts[(nseg + k) * 72 + cl] = sv[k];
  __syncthreads();
  {
    unsigned short* dst = saT_pk + (size_t)b * N_ * C_;
#pragma unroll
    for (int u = t; u < 512; u += 256) {
      int blk = u >> 6, wi = (u & 63) * 8;
      int rl = (blk >> 1) * 16 + (wi >> 5);
      int kl = (blk & 1) * 32 + (wi & 31);
      int gr = n0 + rl, gk = c0 + kl;
      size_t go = ((size_t)(gr >> 4) * 16 + (gk >> 5)) * 512 + (gr & 15) * 32 + (gk & 31);
      *(int4*)&dst[go] = *(int4*)&ts[rl * 72 + kl];
    }
  }
}

// ---------------------------------------------------------------------------
// K_cam_e: e_part[ks][b][c][d] = scale * sum_n sa_c sa_d.  64x64 tile, ks4.
// ---------------------------------------------------------------------------
__global__ __launch_bounds__(256) void k_cam_e(const unsigned short* __restrict__ sa_pk,
                                               float* __restrict__ e_part) {
  const int b = blockIdx.z, ks = blockIdx.y;
  const int c0 = (blockIdx.x & 7) * 64, d0 = (blockIdx.x >> 3) * 64;
  const int t = threadIdx.x, wave = t >> 6, lane = t & 63;
  const int la = lane & 15, quad = lane >> 4;
  const int cw = wave & 1, dw = wave >> 1;
  const int lanelin = la * 32 + quad * 8;
  const unsigned short* sb = sa_pk + (size_t)b * C_ * N_;

  v4f acc[2][2];
#pragma unroll
  for (int i = 0; i < 2; ++i)
#pragma unroll
    for (int j = 0; j < 2; ++j) acc[i][j] = (v4f){0.f, 0.f, 0.f, 0.f};

  const int ar16 = (c0 + cw * 32) >> 4;
  const int br16 = (d0 + dw * 32) >> 4;
#pragma unroll 4
  for (int s = 0; s < 32; ++s) {
    const int k32 = ks * 32 + s;
    v8s a0 = ld8(&sb[((size_t)(ar16 + 0) * 128 + k32) * 512 + lanelin]);
    v8s a1 = ld8(&sb[((size_t)(ar16 + 1) * 128 + k32) * 512 + lanelin]);
    v8s b0 = ld8(&sb[((size_t)(br16 + 0) * 128 + k32) * 512 + lanelin]);
    v8s b1 = ld8(&sb[((size_t)(br16 + 1) * 128 + k32) * 512 + lanelin]);
    acc[0][0] = mfma16(a0, b0, acc[0][0]);
    acc[0][1] = mfma16(a0, b1, acc[0][1]);
    acc[1][0] = mfma16(a1, b0, acc[1][0]);
    acc[1][1] = mfma16(a1, b1, acc[1][1]);
  }
  float* ep = e_part + ((size_t)(ks * B_ + b)) * C_ * C_;
#pragma unroll
  for (int i = 0; i < 2; ++i)
#pragma unroll
    for (int j = 0; j < 2; ++j)
#pragma unroll
      for (int r = 0; r < 4; ++r) {
        int c = c0 + cw * 32 + i * 16 + quad * 4 + r;
        int d = d0 + dw * 32 + j * 16 + la;
        ep[(size_t)c * C_ + d] = acc[i][j][r] * SCALE_CAM;
      }
}

// ---------------------------------------------------------------------------
// K_cam_softmax: min-trick softmax over 4 parts -> attn_pk PK(512,512).
// ---------------------------------------------------------------------------
__global__ __launch_bounds__(64) void k_cam_softmax(const float* __restrict__ e_part,
                                                    unsigned short* __restrict__ attn_pk) {
  const int c = blockIdx.x, b = blockIdx.y, lane = threadIdx.x;
  size_t roff = ((size_t)b * C_ + c) * C_;
  float vals[8];
#pragma unroll
  for (int r = 0; r < 8; ++r) {
    int d = lane + r * 64;
    float s = 0.f;
#pragma unroll
    for (int p = 0; p < 4; ++p) s += e_part[(size_t)(p * B_) * C_ * C_ + roff + d];
    vals[r] = s;
  }
  float mn = vals[0];
#pragma unroll
  for (int r = 1; r < 8; ++r) mn = fminf(mn, vals[r]);
#pragma unroll
  for (int m = 32; m >= 1; m >>= 1) mn = fminf(mn, __shfl_xor(mn, m));
  float sum = 0.f;
#pragma unroll
  for (int r = 0; r < 8; ++r) { vals[r] = __expf(mn - vals[r]); sum += vals[r]; }
#pragma unroll
  for (int m = 32; m >= 1; m >>= 1) sum += __shfl_xor(sum, m);
  float sc = (1.0f / (float)C_) / sum;
  unsigned short* ab = attn_pk + (size_t)b * C_ * C_;
#pragma unroll
  for (int r = 0; r < 8; ++r) {
    int d = lane + r * 64;
    size_t go = ((size_t)(c >> 4) * 16 + (d >> 5)) * 512 + (c & 15) * 32 + (d & 31);
    ab[go] = f2bf(vals[r] * sc);
  }
}

// ---------------------------------------------------------------------------
// K_cam_out: out = gc * (attn @ sa) + sa.  128c x 128n tile, 512 thr.
// ---------------------------------------------------------------------------
__global__ __launch_bounds__(512) void k_cam_out(
    const unsigned short* __restrict__ attn_pk, const unsigned short* __restrict__ saT_pk,
    const unsigned short* __restrict__ sa_pk, const float* __restrict__ gamma_cam,
    float* __restrict__ out) {
  const int b = blockIdx.z, c0 = blockIdx.y * 128, n0 = blockIdx.x * 128;
  const int t = threadIdx.x, wave = t >> 6, lane = t & 63;
  const int la = lane & 15, quad = lane >> 4;
  const int cw = wave & 1, nw = wave >> 1;
  const int lanelin = la * 32 + quad * 8;
  const unsigned short* ab = attn_pk + (size_t)b * C_ * C_;
  const unsigned short* sTb = saT_pk + (size_t)b * N_ * C_;
  const unsigned short* sb = sa_pk + (size_t)b * C_ * N_;

  v4f acc[4][2];
#pragma unroll
  for (int i = 0; i < 4; ++i)
#pragma unroll
    for (int j = 0; j < 2; ++j) acc[i][j] = (v4f){0.f, 0.f, 0.f, 0.f};

  const int ar16 = (c0 + cw * 64) >> 4;
  const int br16 = (n0 + nw * 32) >> 4;
#pragma unroll 4
  for (int s = 0; s < 16; ++s) {
    v8s b0 = ld8(&sTb[((size_t)(br16 + 0) * 16 + s) * 512 + lanelin]);
    v8s b1 = ld8(&sTb[((size_t)(br16 + 1) * 16 + s) * 512 + lanelin]);
#pragma unroll
    for (int ci = 0; ci < 4; ++ci) {
      v8s a = ld8(&ab[((size_t)(ar16 + ci) * 16 + s) * 512 + lanelin]);
      acc[ci][0] = mfma16(a, b0, acc[ci][0]);
      acc[ci][1] = mfma16(a, b1, acc[ci][1]);
    }
  }
  const float gc = gamma_cam[0];
#pragma unroll
  for (int ci = 0; ci < 4; ++ci)
#pragma unroll
    for (int nj = 0; nj < 2; ++nj)
#pragma unroll
      for (int r = 0; r < 4; ++r) {
        int c = c0 + cw * 64 + ci * 16 + quad * 4 + r;
        int n = n0 + nw * 32 + nj * 16 + la;
        size_t pko = ((size_t)(c >> 4) * 128 + (n >> 5)) * 512 + (c & 15) * 32 + (n & 31);
        out[((size_t)b * C_ + c) * N_ + n] = fmaf(gc, acc[ci][nj][r], bf2f(sb[pko]));
      }
}

// ---------------------------------------------------------------------------
extern "C" void kernel_launch(void* const* d_in, const int* in_sizes, int n_in,
                              void* d_out, int out_size, void* d_ws, size_t ws_size,
                              hipStream_t stream) {
  const float* x  = (const float*)d_in[0];
  const float* wq = (const float*)d_in[1];
  const float* bq = (const float*)d_in[2];
  const float* wk = (const float*)d_in[3];
  const float* bk = (const float*)d_in[4];
  const float* wv = (const float*)d_in[5];
  const float* bv = (const float*)d_in[6];
  const float* gp = (const float*)d_in[7];
  const float* gc = (const float*)d_in[8];
  float* out = (float*)d_out;

  char* ws = (char*)d_ws;
  // Region map (with reuse; total 118.62 MB):
  //  A 0        : x_pk (16.78M)  -> later sa_pk
  //  B 16.78M   : w_pk (1.05M)
  //  C 17.83M   : q_pk (8.39M)   -> later saT_pk (spans C..C+16.78M with k_pk)
  //  D 26.21M   : k_pk (8.39M)
  //  E 34.60M   : v_pk (16.78M)  -> later ep
  //  F 51.38M   : acc_part (67.11M) -> later at_pk (first 2.1M)
  //  G 118.49M  : l_part (128KB)
  unsigned short* x_pk   = (unsigned short*)(ws);
  unsigned short* w_pk   = (unsigned short*)(ws + 16777216);
  unsigned short* q_pk   = (unsigned short*)(ws + 17825792);
  unsigned short* k_pk   = (unsigned short*)(ws + 26214400);
  unsigned short* v_pk   = (unsigned short*)(ws + 34603008);
  float*          acc_p  = (float*)(ws + 51380224);
  float*          l_p    = (float*)(ws + 118489088);
  unsigned short* sa_pk  = (unsigned short*)(ws);              // reuse A
  unsigned short* saT_pk = (unsigned short*)(ws + 17825792);   // reuse C+D
  float*          ep     = (float*)(ws + 34603008);            // reuse E
  unsigned short* at_pk  = (unsigned short*)(ws + 51380224);   // reuse F

  k_xT<<<dim3(64, 8, B_), 256, 0, stream>>>(x, x_pk);
  k_wb<<<256, 256, 0, stream>>>(wq, wk, wv, w_pk);
  k_qkv<<<dim3(32, 8, B_), 512, 0, stream>>>(w_pk, x_pk, bq, bk, bv, q_pk, k_pk, v_pk);
  k_pam<<<512, 1024, 0, stream>>>(q_pk, k_pk, v_pk, acc_p, l_p);
  k_combine<<<dim3(64, 8, B_), 256, 0, stream>>>(acc_p, l_p, x, gp, sa_pk, saT_pk);
  k_cam_e<<<dim3(64, 4, B_), 256, 0, stream>>>(sa_pk, ep);
  k_cam_softmax<<<dim3(C_, B_), 64, 0, stream>>>(ep, at_pk);
  k_cam_out<<<dim3(32, 4, B_), 512, 0, stream>>>(at_pk, saT_pk, sa_pk, gc, out);
}